// Round 17
// baseline (79.944 us; speedup 1.0000x reference)
//
#include <hip/hip_runtime.h>

#define NB 8192
#define EPS_BN 1e-5f

// padded LDS index: +4 floats every 32 => stride-16B lane patterns are
// conflict-free while float4/float2 alignment is preserved (4 | pad).
#define PADX(i) ((i) + ((((i) >> 5)) << 2))

using bf16x8 = __attribute__((ext_vector_type(8))) __bf16;
using bf16x4 = __attribute__((ext_vector_type(4))) __bf16;
using f32x4  = __attribute__((ext_vector_type(4))) float;
using f32x2  = __attribute__((ext_vector_type(2))) float;
using u32x4  = __attribute__((ext_vector_type(4))) unsigned int;

// d_ws layout (float offsets relative to wsf = d_ws + 1MB):
//   0 wA1[64] | 64 bA1[8] | 80 wB2[640] | 720 bB2[16] | 736 wC3[1536] | 2272 bC3[32]
//   2560 wih_p | 4608 whh_p | 6656 fc1_p | 8704 fc2_p | 9728 fc3_p
//   9984 bfr_p | 10112 fc1b_p | 10176 fc2b_p | 10208 fc3b_p | 12288 spatial_bf16
#define WSF_OFF 262144
#define PK_WIH  2560
#define PK_WHH  4608
#define PK_FC1  6656
#define PK_FC2  8704
#define PK_FC3  9728
#define PK_BFR  9984
#define PK_B1   10112
#define PK_B2   10176
#define PK_B3   10208
#define PK_SPB  12288

__device__ inline unsigned pack_bf16(float a, float b) {
    union { __bf16 h; unsigned short u; } ca, cb;
    ca.h = (__bf16)a; cb.h = (__bf16)b;
    return (unsigned)ca.u | ((unsigned)cb.u << 16);
}

// ---------------------------------------------------------------------------
// Kernel 0: fold BN into conv weights + prepack lstm/fc fragments (UNCHANGED).
// ---------------------------------------------------------------------------
__global__ __launch_bounds__(256) void fold_kernel(
    const float* __restrict__ w1, const float* __restrict__ b1,
    const float* __restrict__ g1, const float* __restrict__ be1,
    const float* __restrict__ m1, const float* __restrict__ v1,
    const float* __restrict__ w2, const float* __restrict__ b2,
    const float* __restrict__ g2, const float* __restrict__ be2,
    const float* __restrict__ m2, const float* __restrict__ v2,
    const float* __restrict__ w3, const float* __restrict__ b3,
    const float* __restrict__ g3, const float* __restrict__ be3,
    const float* __restrict__ m3, const float* __restrict__ v3,
    const float* __restrict__ w_ih, const float* __restrict__ w_hh,
    const float* __restrict__ b_ih, const float* __restrict__ b_hh,
    const float* __restrict__ fc1w, const float* __restrict__ fc1b,
    const float* __restrict__ fc2w, const float* __restrict__ fc2b,
    const float* __restrict__ fc3w, const float* __restrict__ fc3b,
    float* __restrict__ wsf)
{
    int j = blockIdx.x * 256 + threadIdx.x;
    if (j < 64) {
        int k = j >> 3, c = j & 7;
        wsf[j] = (k < 7) ? w1[c * 7 + k] * (g1[c] * rsqrtf(v1[c] + EPS_BN)) : 0.f;
    } else if (j < 72) {
        int c = j - 64;
        float inv = g1[c] * rsqrtf(v1[c] + EPS_BN);
        wsf[j] = (b1[c] - m1[c]) * inv + be1[c];
    } else if (j >= 80 && j < 720) {
        int i = j - 80, c = i & 15, t = i >> 4, ci = t / 5, k = t - 5 * ci;
        wsf[j] = w2[(c * 8 + ci) * 5 + k] * (g2[c] * rsqrtf(v2[c] + EPS_BN));
    } else if (j >= 720 && j < 736) {
        int c = j - 720;
        float inv = g2[c] * rsqrtf(v2[c] + EPS_BN);
        wsf[j] = (b2[c] - m2[c]) * inv + be2[c];
    } else if (j >= 736 && j < 2272) {
        int i = j - 736, c = i & 31, t = i >> 5, ci = t / 3, k = t - 3 * ci;
        wsf[j] = w3[(c * 16 + ci) * 3 + k] * (g3[c] * rsqrtf(v3[c] + EPS_BN));
    } else if (j >= 2272 && j < 2304) {
        int c = j - 2272;
        float inv = g3[c] * rsqrtf(v3[c] + EPS_BN);
        wsf[j] = (b3[c] - m3[c]) * inv + be3[c];
    } else if (j >= 2560 && j < 3072) {
        int idx = j - 2560, T = idx >> 6, j6 = idx & 63, row = j6 & 15, q = j6 >> 4;
        const float* src = w_ih + (size_t)(16 * T + row) * 32 + 8 * q;
        unsigned* dst = (unsigned*)(wsf + PK_WIH) + (size_t)idx * 4;
        #pragma unroll
        for (int i = 0; i < 4; i++) dst[i] = pack_bf16(src[2 * i], src[2 * i + 1]);
    } else if (j >= 3072 && j < 3584) {
        int idx = j - 3072, T = idx >> 6, j6 = idx & 63, row = j6 & 15, q = j6 >> 4;
        const float* src = w_hh + (size_t)(16 * T + row) * 32 + 8 * q;
        unsigned* dst = (unsigned*)(wsf + PK_WHH) + (size_t)idx * 4;
        #pragma unroll
        for (int i = 0; i < 4; i++) dst[i] = pack_bf16(src[2 * i], src[2 * i + 1]);
    } else if (j >= 3584 && j < 4096) {
        int idx = j - 3584, f = idx >> 6, j6 = idx & 63, row = j6 & 15, q = j6 >> 4;
        int T = f >> 1, s = f & 1;
        const float* src = fc1w + (size_t)(16 * T + row) * 64 + 32 * s + 8 * q;
        unsigned* dst = (unsigned*)(wsf + PK_FC1) + (size_t)idx * 4;
        #pragma unroll
        for (int i = 0; i < 4; i++) dst[i] = pack_bf16(src[2 * i], src[2 * i + 1]);
    } else if (j >= 4096 && j < 4352) {
        int idx = j - 4096, f = idx >> 6, j6 = idx & 63, row = j6 & 15, q = j6 >> 4;
        int T = f >> 1, s = f & 1;
        const float* src = fc2w + (size_t)(16 * T + row) * 64 + 32 * s + 8 * q;
        unsigned* dst = (unsigned*)(wsf + PK_FC2) + (size_t)idx * 4;
        #pragma unroll
        for (int i = 0; i < 4; i++) dst[i] = pack_bf16(src[2 * i], src[2 * i + 1]);
    } else if (j >= 4352 && j < 4416) {
        int j6 = j - 4352, row = j6 & 15, q = j6 >> 4;
        const float* src = fc3w + (size_t)(row & 3) * 32 + 8 * q;
        unsigned* dst = (unsigned*)(wsf + PK_FC3) + (size_t)j6 * 4;
        #pragma unroll
        for (int i = 0; i < 4; i++) dst[i] = pack_bf16(src[2 * i], src[2 * i + 1]);
    } else if (j >= 4416 && j < 4448) {
        int idx = j - 4416, T = idx >> 2, q = idx & 3;
        #pragma unroll
        for (int i = 0; i < 4; i++)
            wsf[PK_BFR + idx * 4 + i] = b_ih[16 * T + 4 * q + i] + b_hh[16 * T + 4 * q + i];
    } else if (j >= 4448 && j < 4464) {
        int idx = j - 4448, T = idx >> 2, q = idx & 3;
        #pragma unroll
        for (int i = 0; i < 4; i++) wsf[PK_B1 + idx * 4 + i] = fc1b[16 * T + 4 * q + i];
    } else if (j >= 4464 && j < 4472) {
        int idx = j - 4464, T = idx >> 2, q = idx & 3;
        #pragma unroll
        for (int i = 0; i < 4; i++) wsf[PK_B2 + idx * 4 + i] = fc2b[16 * T + 4 * q + i];
    } else if (j == 4472) {
        #pragma unroll
        for (int i = 0; i < 4; i++) wsf[PK_B3 + i] = fc3b[i];
    }
}

// ---------------------------------------------------------------------------
// Kernel 1: conv stack + LIF — ONE WAVE PER BATCH ELEMENT with EXPLICIT
// per-phase __syncthreads() (single-wave block: barrier = lgkmcnt(0)+s_barrier,
// no cross-wave coupling; r16's barrier-free version failed -> the implicit
// intra-wave LDS ordering assumption was unsound at this code size).
// conv1: lane = 4 positions x 8 ch. conv2: lane = pos x 16 ch. conv3:
// pos = l&31 (upper half duplicates, predicated writes), 32 ch.
// All weight indices wave-uniform -> scalar s_load. LDS 14.2 KB, ~11 blk/CU.
// Per-channel accumulation order: ci-major, k-minor (bit-identical r12-r15).
// ---------------------------------------------------------------------------
__device__ inline f32x2 pkfma(f32x2 a, f32x2 b, f32x2 c) {
    return __builtin_elementwise_fma(a, b, c);
}

__global__ __launch_bounds__(64) void conv_lif_kernel(
    const float* __restrict__ x,
    const float* __restrict__ wsf,          // folded weights (s_load)
    unsigned short* __restrict__ spb,       // spatial bf16 out (wsf+PK_SPB)
    float* __restrict__ spatial_out,        // [B][32]
    unsigned int* __restrict__ spk)         // [B][32] bitmask per (b,t)
{
    // {c1 | c3} alias: c1 = 8 x 292 (idx pos+2, PADX), c3 = 32 x 33
    // c2 = 16 x 76 (idx pos+1, PADX)
    __shared__ alignas(16) float smem[3552];
    float* const c1 = smem;
    float* const c3 = smem;
    float* const c2 = smem + 2336;

    const int b = blockIdx.x;
    const int l = threadIdx.x;              // 0..63
    const float* xb = x + (size_t)b * 1024;

    // front zeros
    if (l < 8) { c1[l * 292] = 0.f; c1[l * 292 + 1] = 0.f; }
    if (l < 16) c2[l * 76] = 0.f;

    // ---- conv1: lane l -> positions 4l..4l+3, 8 ch as 4 pk-pairs ----
    {
        float4 xv0 = make_float4(0.f, 0.f, 0.f, 0.f);
        if (l > 0) xv0 = *reinterpret_cast<const float4*>(xb + 16 * l - 4);
        float4 xv1 = *reinterpret_cast<const float4*>(xb + 16 * l);
        float4 xv2 = *reinterpret_cast<const float4*>(xb + 16 * l + 4);
        float4 xv3 = *reinterpret_cast<const float4*>(xb + 16 * l + 8);
        float4 xv4 = *reinterpret_cast<const float4*>(xb + 16 * l + 12);
        float xw[20] = {xv0.x, xv0.y, xv0.z, xv0.w,
                        xv1.x, xv1.y, xv1.z, xv1.w,
                        xv2.x, xv2.y, xv2.z, xv2.w,
                        xv3.x, xv3.y, xv3.z, xv3.w,
                        xv4.x, xv4.y, xv4.z, xv4.w};
        #pragma unroll
        for (int i = 0; i < 4; i++) {
            const int p = 4 * l + i;
            #pragma unroll
            for (int cp = 0; cp < 4; cp++) {
                f32x2 acc = *reinterpret_cast<const f32x2*>(wsf + 64 + 2 * cp);
                #pragma unroll
                for (int k = 0; k < 7; k++) {
                    f32x2 wv = *reinterpret_cast<const f32x2*>(wsf + k * 8 + 2 * cp);
                    f32x2 sv = {xw[4 * i + 1 + k], xw[4 * i + 1 + k]};
                    acc = pkfma(wv, sv, acc);
                }
                c1[(2 * cp + 0) * 292 + PADX(2 + p)] = fmaxf(acc[0], 0.f);
                c1[(2 * cp + 1) * 292 + PADX(2 + p)] = fmaxf(acc[1], 0.f);
            }
        }
    }
    __syncthreads();                        // c1 (+zeros) visible

    // ---- conv2: lane = pos (64), ALL 16 ch as 8 pk-pairs ----
    {
        const float* wB2 = wsf + 80;
        const float* bB2 = wsf + 720;
        f32x2 a[8];
        #pragma unroll
        for (int pr = 0; pr < 8; pr++)
            a[pr] = *reinterpret_cast<const f32x2*>(bB2 + 2 * pr);
        #pragma unroll
        for (int ci = 0; ci < 8; ci++) {
            const float* row = c1 + ci * 292;
            float4 va = *reinterpret_cast<const float4*>(&row[PADX(4 * l)]);
            float  v4 = row[PADX(4 * l + 4)];
            float win[5] = {va.x, va.y, va.z, va.w, v4};
            #pragma unroll
            for (int k = 0; k < 5; k++) {
                const float* wp = wB2 + (ci * 5 + k) * 16;   // uniform -> s_load
                f32x2 sv = {win[k], win[k]};
                #pragma unroll
                for (int pr = 0; pr < 8; pr++)
                    a[pr] = pkfma(*reinterpret_cast<const f32x2*>(wp + 2 * pr), sv, a[pr]);
            }
        }
        #pragma unroll
        for (int pr = 0; pr < 8; pr++) {
            c2[(2 * pr + 0) * 76 + PADX(1 + l)] = fmaxf(a[pr][0], 0.f);
            c2[(2 * pr + 1) * 76 + PADX(1 + l)] = fmaxf(a[pr][1], 0.f);
        }
    }
    __syncthreads();                        // c2 (+zero) visible

    // ---- conv3: pos = l&31 (upper half duplicates), ALL 32 ch ----
    {
        const int p3 = l & 31;
        const float* wC3 = wsf + 736;
        const float* bC3 = wsf + 2272;
        f32x2 a[16];
        #pragma unroll
        for (int pr = 0; pr < 16; pr++)
            a[pr] = *reinterpret_cast<const f32x2*>(bC3 + 2 * pr);
        #pragma unroll
        for (int ci = 0; ci < 16; ci++) {
            const float* row = c2 + ci * 76;
            float2 vab = *reinterpret_cast<const float2*>(&row[PADX(2 * p3)]);
            float  vc  = row[PADX(2 * p3 + 2)];
            float win[3] = {vab.x, vab.y, vc};
            #pragma unroll
            for (int k = 0; k < 3; k++) {
                const float* wp = wC3 + (ci * 3 + k) * 32;   // uniform -> s_load
                f32x2 sv = {win[k], win[k]};
                #pragma unroll
                for (int pr = 0; pr < 16; pr++)
                    a[pr] = pkfma(*reinterpret_cast<const f32x2*>(wp + 2 * pr), sv, a[pr]);
            }
        }
        if (l < 32) {
            #pragma unroll
            for (int pr = 0; pr < 16; pr++) {
                c3[(2 * pr + 0) * 33 + p3] = fmaxf(a[pr][0], 0.f);
                c3[(2 * pr + 1) * 33 + p3] = fmaxf(a[pr][1], 0.f);
            }
        }
    }
    __syncthreads();                        // c3 visible

    // ---- spatial mean + LIF scan (lanes 0..31 = channels) ----
    if (l < 32) {
        float s = 0.f;
        #pragma unroll
        for (int t = 0; t < 32; t++) s += c3[l * 33 + t];
        float sv = s * 0.03125f;
        spatial_out[(size_t)b * 32 + l] = sv;
        union { __bf16 h; unsigned short u; } cv;
        cv.h = (__bf16)sv;
        spb[(size_t)b * 32 + l] = cv.u;

        float mem = 0.f;
        #pragma unroll
        for (int t = 0; t < 32; t++) {
            mem = __fadd_rn(__fmul_rn(0.9f, mem), c3[l * 33 + t]);
            bool spike = mem > 0.5f;
            mem = spike ? 0.f : mem;
            unsigned long long msk = __ballot(spike);
            if (l == 0) spk[(size_t)b * 32 + t] = (unsigned int)(msk & 0xffffffffull);
        }
    }
}

// ---------------------------------------------------------------------------
// Kernel 2: MFMA LSTM + FC head — 4-wave gate-split (UNCHANGED from r15).
// ---------------------------------------------------------------------------
__device__ inline float sigm(float x) {
    return __builtin_amdgcn_rcpf(1.f + __expf(-x));
}
__device__ inline float tanh_(float x) {
    return fmaf(2.f, __builtin_amdgcn_rcpf(1.f + __expf(-2.f * x)), -1.f);
}

__global__ __launch_bounds__(256, 2) void lstm_fc_mfma_kernel(
    const unsigned int* __restrict__ spk,   // [B][32]
    const float* __restrict__ wsf,          // prepacked weights + spatial_bf
    float* __restrict__ out0,               // [B][4]
    float* __restrict__ hlast_out)          // [B][32]
{
    const int ltid = threadIdx.x;
    const int l    = ltid & 63;
    const int g    = ltid >> 6;             // wave = gate (0=i,1=f,2=g,3=o)
    const int row  = l & 15;
    const int q    = l >> 4;
    const int base = blockIdx.x * 16;

    __shared__ unsigned int mlds[512];           // [t][16]
    __shared__ alignas(16) __bf16 hdb[640];      // h: [16][40]
    __shared__ alignas(16) float  actb[2304];    // acts: [4][16][36]
    __shared__ alignas(16) __bf16 zlds[1152];    // fc1 out: [16][72]

    for (int i = ltid; i < 512; i += 256) {
        int j = i >> 5, t = i & 31;
        mlds[t * 16 + j] = spk[(size_t)(base + j) * 32 + t];
    }
    for (int i = ltid; i < 640; i += 256) hdb[i] = (__bf16)0.f;

    union bc { u32x4 u; bf16x8 v; };
    const u32x4* wihp = (const u32x4*)(wsf + PK_WIH);
    const u32x4* whhp = (const u32x4*)(wsf + PK_WHH);

    const int T0 = 2 * g, T1 = 2 * g + 1;
    bf16x8 wih0, wih1, whh0, whh1;
    { bc a; a.u = wihp[T0 * 64 + l]; wih0 = a.v; }
    { bc a; a.u = wihp[T1 * 64 + l]; wih1 = a.v; }
    { bc a; a.u = whhp[T0 * 64 + l]; whh0 = a.v; }
    { bc a; a.u = whhp[T1 * 64 + l]; whh1 = a.v; }
    f32x4 bfr0 = *reinterpret_cast<const f32x4*>(wsf + PK_BFR + (T0 * 4 + q) * 4);
    f32x4 bfr1 = *reinterpret_cast<const f32x4*>(wsf + PK_BFR + (T1 * 4 + q) * 4);

    const float as = (g == 2) ? 2.f : 1.f;
    const float am = (g == 2) ? 2.f : 1.f;
    const float ac = (g == 2) ? -1.f : 0.f;

    const int crow = ltid & 15, cci = ltid >> 4;
    float cst0 = 0.f, cst1 = 0.f, h0 = 0.f, h1 = 0.f;

    __syncthreads();

    #pragma unroll 1
    for (int t = 0; t < 32; t++) {
        unsigned int m  = mlds[t * 16 + row];
        unsigned int by = (m >> (q * 8)) & 0xFFu;
        union { bf16x8 v; unsigned int u[4]; } a1;
        a1.u[0] = ((by & 1u)        * 0x3F80u) | (((by >> 1) & 1u) * 0x3F800000u);
        a1.u[1] = (((by >> 2) & 1u) * 0x3F80u) | (((by >> 3) & 1u) * 0x3F800000u);
        a1.u[2] = (((by >> 4) & 1u) * 0x3F80u) | (((by >> 5) & 1u) * 0x3F800000u);
        a1.u[3] = (((by >> 6) & 1u) * 0x3F80u) | (((by >> 7) & 1u) * 0x3F800000u);
        bf16x8 a2 = *reinterpret_cast<bf16x8*>(&hdb[row * 40 + q * 8]);

        f32x4 acc0 = __builtin_amdgcn_mfma_f32_16x16x32_bf16(wih0, a1.v, bfr0, 0, 0, 0);
        acc0       = __builtin_amdgcn_mfma_f32_16x16x32_bf16(whh0, a2,   acc0, 0, 0, 0);
        f32x4 acc1 = __builtin_amdgcn_mfma_f32_16x16x32_bf16(wih1, a1.v, bfr1, 0, 0, 0);
        acc1       = __builtin_amdgcn_mfma_f32_16x16x32_bf16(whh1, a2,   acc1, 0, 0, 0);

        f32x4 e0, e1;
        #pragma unroll
        for (int j = 0; j < 4; j++) {
            e0[j] = fmaf(am, sigm(as * acc0[j]), ac);
            e1[j] = fmaf(am, sigm(as * acc1[j]), ac);
        }
        *reinterpret_cast<f32x4*>(&actb[g * 576 + row * 36 + 4 * q])      = e0;
        *reinterpret_cast<f32x4*>(&actb[g * 576 + row * 36 + 16 + 4 * q]) = e1;
        __syncthreads();

        {
            float iv0 = actb[0 * 576 + crow * 36 + cci];
            float fv0 = actb[1 * 576 + crow * 36 + cci];
            float gv0 = actb[2 * 576 + crow * 36 + cci];
            float ov0 = actb[3 * 576 + crow * 36 + cci];
            float iv1 = actb[0 * 576 + crow * 36 + 16 + cci];
            float fv1 = actb[1 * 576 + crow * 36 + 16 + cci];
            float gv1 = actb[2 * 576 + crow * 36 + 16 + cci];
            float ov1 = actb[3 * 576 + crow * 36 + 16 + cci];
            cst0 = fmaf(fv0, cst0, iv0 * gv0);
            h0   = ov0 * tanh_(cst0);
            cst1 = fmaf(fv1, cst1, iv1 * gv1);
            h1   = ov1 * tanh_(cst1);
            hdb[crow * 40 + cci]      = (__bf16)h0;
            hdb[crow * 40 + 16 + cci] = (__bf16)h1;
        }
        __syncthreads();
    }

    hlast_out[(size_t)(base + crow) * 32 + cci]      = h0;
    hlast_out[(size_t)(base + crow) * 32 + 16 + cci] = h1;

    bf16x8 hf = *reinterpret_cast<bf16x8*>(&hdb[row * 40 + 8 * q]);
    bf16x8 spf;
    {
        bc s_;
        s_.u = *reinterpret_cast<const u32x4*>(
            (const unsigned short*)(wsf + PK_SPB) + (size_t)(base + row) * 32 + 8 * q);
        spf = s_.v;
    }

    const u32x4* fc1p = (const u32x4*)(wsf + PK_FC1);
    {
        const int T = g;
        bc x0_, x1_;
        x0_.u = fc1p[(T * 2 + 0) * 64 + l];
        x1_.u = fc1p[(T * 2 + 1) * 64 + l];
        f32x4 c = *reinterpret_cast<const f32x4*>(wsf + PK_B1 + (T * 4 + q) * 4);
        f32x4 a = __builtin_amdgcn_mfma_f32_16x16x32_bf16(x0_.v, hf,  c, 0, 0, 0);
        a       = __builtin_amdgcn_mfma_f32_16x16x32_bf16(x1_.v, spf, a, 0, 0, 0);
        bf16x4 zv;
        #pragma unroll
        for (int i = 0; i < 4; i++) zv[i] = (__bf16)fmaxf(a[i], 0.f);
        *reinterpret_cast<bf16x4*>(&zlds[row * 72 + 16 * T + 4 * q]) = zv;
    }
    __syncthreads();
    bf16x8 z1f0 = *reinterpret_cast<bf16x8*>(&zlds[row * 72 + 8 * q]);
    bf16x8 z1f1 = *reinterpret_cast<bf16x8*>(&zlds[row * 72 + 32 + 8 * q]);

    __bf16* z2b = (__bf16*)actb;
    const u32x4* fc2p = (const u32x4*)(wsf + PK_FC2);
    if (g < 2) {
        const int T = g;
        bc x0_, x1_;
        x0_.u = fc2p[(T * 2 + 0) * 64 + l];
        x1_.u = fc2p[(T * 2 + 1) * 64 + l];
        f32x4 c = *reinterpret_cast<const f32x4*>(wsf + PK_B2 + (T * 4 + q) * 4);
        f32x4 a = __builtin_amdgcn_mfma_f32_16x16x32_bf16(x0_.v, z1f0, c, 0, 0, 0);
        a       = __builtin_amdgcn_mfma_f32_16x16x32_bf16(x1_.v, z1f1, a, 0, 0, 0);
        bf16x4 zv;
        #pragma unroll
        for (int i = 0; i < 4; i++) zv[i] = (__bf16)fmaxf(a[i], 0.f);
        *reinterpret_cast<bf16x4*>(&z2b[row * 40 + 16 * T + 4 * q]) = zv;
    }
    __syncthreads();

    if (g == 0) {
        bf16x8 z2f = *reinterpret_cast<bf16x8*>(&z2b[row * 40 + 8 * q]);
        bc x3_;
        x3_.u = ((const u32x4*)(wsf + PK_FC3))[l];
        f32x4 c = *reinterpret_cast<const f32x4*>(wsf + PK_B3);
        f32x4 o = __builtin_amdgcn_mfma_f32_16x16x32_bf16(x3_.v, z2f, c, 0, 0, 0);
        if (l < 16)
            *reinterpret_cast<f32x4*>(out0 + (size_t)(base + row) * 4) = o;
    }
}

// ---------------------------------------------------------------------------
extern "C" void kernel_launch(void* const* d_in, const int* in_sizes, int n_in,
                              void* d_out, int out_size, void* d_ws, size_t ws_size,
                              hipStream_t stream) {
    const float* x    = (const float*)d_in[0];
    const float* w1   = (const float*)d_in[1];
    const float* b1   = (const float*)d_in[2];
    const float* g1   = (const float*)d_in[3];
    const float* be1  = (const float*)d_in[4];
    const float* m1   = (const float*)d_in[5];
    const float* v1   = (const float*)d_in[6];
    const float* w2   = (const float*)d_in[7];
    const float* b2   = (const float*)d_in[8];
    const float* g2   = (const float*)d_in[9];
    const float* be2  = (const float*)d_in[10];
    const float* m2   = (const float*)d_in[11];
    const float* v2   = (const float*)d_in[12];
    const float* w3   = (const float*)d_in[13];
    const float* b3   = (const float*)d_in[14];
    const float* g3   = (const float*)d_in[15];
    const float* be3  = (const float*)d_in[16];
    const float* m3   = (const float*)d_in[17];
    const float* v3   = (const float*)d_in[18];
    const float* w_ih = (const float*)d_in[19];
    const float* w_hh = (const float*)d_in[20];
    const float* b_ih = (const float*)d_in[21];
    const float* b_hh = (const float*)d_in[22];
    const float* fc1w = (const float*)d_in[23];
    const float* fc1b = (const float*)d_in[24];
    const float* fc2w = (const float*)d_in[25];
    const float* fc2b = (const float*)d_in[26];
    const float* fc3w = (const float*)d_in[27];
    const float* fc3b = (const float*)d_in[28];

    float* out0    = (float*)d_out;                 // [8192][4]
    float* spatial = out0 + (size_t)NB * 4;         // [8192][32]
    float* hlast   = spatial + (size_t)NB * 32;     // [8192][32]
    unsigned int* spk = (unsigned int*)d_ws;        // [8192][32] bitmasks
    float* wsf = (float*)d_ws + WSF_OFF;            // folded + prepacked weights
    unsigned short* spb = (unsigned short*)(wsf + PK_SPB);

    hipLaunchKernelGGL(fold_kernel, dim3(18), dim3(256), 0, stream,
                       w1, b1, g1, be1, m1, v1,
                       w2, b2, g2, be2, m2, v2,
                       w3, b3, g3, be3, m3, v3,
                       w_ih, w_hh, b_ih, b_hh,
                       fc1w, fc1b, fc2w, fc2b, fc3w, fc3b, wsf);

    hipLaunchKernelGGL(conv_lif_kernel, dim3(NB), dim3(64), 0, stream,
                       x, wsf, spb, spatial, spk);

    hipLaunchKernelGGL(lstm_fc_mfma_kernel, dim3(NB / 16), dim3(256), 0, stream,
                       spk, wsf, out0, hlast);
}

// Round 18
// 63.265 us; speedup vs baseline: 1.2636x; 1.2636x over previous
//
#include <hip/hip_runtime.h>

#define NB 8192
#define EPS_BN 1e-5f

// padded LDS index: +4 floats every 32 => stride-16B lane patterns are
// conflict-free while float4/float2 alignment is preserved (4 | pad).
#define PADX(i) ((i) + ((((i) >> 5)) << 2))

using bf16x8 = __attribute__((ext_vector_type(8))) __bf16;
using bf16x4 = __attribute__((ext_vector_type(4))) __bf16;
using f32x4  = __attribute__((ext_vector_type(4))) float;
using f32x2  = __attribute__((ext_vector_type(2))) float;
using u32x4  = __attribute__((ext_vector_type(4))) unsigned int;

// d_ws layout (float offsets relative to wsf = d_ws + 1MB):
//   0 wA1[64] | 64 bA1[8] | 80 wB2[640] | 720 bB2[16] | 736 wC3[1536] | 2272 bC3[32]
//   2560 wih_p | 4608 whh_p | 6656 fc1_p | 8704 fc2_p | 9728 fc3_p
//   9984 bfr_p | 10112 fc1b_p | 10176 fc2b_p | 10208 fc3b_p | 12288 spatial_bf16
#define WSF_OFF 262144
#define PK_WIH  2560
#define PK_WHH  4608
#define PK_FC1  6656
#define PK_FC2  8704
#define PK_FC3  9728
#define PK_BFR  9984
#define PK_B1   10112
#define PK_B2   10176
#define PK_B3   10208
#define PK_SPB  12288

__device__ inline unsigned pack_bf16(float a, float b) {
    union { __bf16 h; unsigned short u; } ca, cb;
    ca.h = (__bf16)a; cb.h = (__bf16)b;
    return (unsigned)ca.u | ((unsigned)cb.u << 16);
}

// ---------------------------------------------------------------------------
// Kernel 0: fold BN into conv weights + prepack lstm/fc fragments.
// ---------------------------------------------------------------------------
__global__ __launch_bounds__(256) void fold_kernel(
    const float* __restrict__ w1, const float* __restrict__ b1,
    const float* __restrict__ g1, const float* __restrict__ be1,
    const float* __restrict__ m1, const float* __restrict__ v1,
    const float* __restrict__ w2, const float* __restrict__ b2,
    const float* __restrict__ g2, const float* __restrict__ be2,
    const float* __restrict__ m2, const float* __restrict__ v2,
    const float* __restrict__ w3, const float* __restrict__ b3,
    const float* __restrict__ g3, const float* __restrict__ be3,
    const float* __restrict__ m3, const float* __restrict__ v3,
    const float* __restrict__ w_ih, const float* __restrict__ w_hh,
    const float* __restrict__ b_ih, const float* __restrict__ b_hh,
    const float* __restrict__ fc1w, const float* __restrict__ fc1b,
    const float* __restrict__ fc2w, const float* __restrict__ fc2b,
    const float* __restrict__ fc3w, const float* __restrict__ fc3b,
    float* __restrict__ wsf)
{
    int j = blockIdx.x * 256 + threadIdx.x;
    if (j < 64) {
        int k = j >> 3, c = j & 7;
        wsf[j] = (k < 7) ? w1[c * 7 + k] * (g1[c] * rsqrtf(v1[c] + EPS_BN)) : 0.f;
    } else if (j < 72) {
        int c = j - 64;
        float inv = g1[c] * rsqrtf(v1[c] + EPS_BN);
        wsf[j] = (b1[c] - m1[c]) * inv + be1[c];
    } else if (j >= 80 && j < 720) {
        int i = j - 80, c = i & 15, t = i >> 4, ci = t / 5, k = t - 5 * ci;
        wsf[j] = w2[(c * 8 + ci) * 5 + k] * (g2[c] * rsqrtf(v2[c] + EPS_BN));
    } else if (j >= 720 && j < 736) {
        int c = j - 720;
        float inv = g2[c] * rsqrtf(v2[c] + EPS_BN);
        wsf[j] = (b2[c] - m2[c]) * inv + be2[c];
    } else if (j >= 736 && j < 2272) {
        int i = j - 736, c = i & 31, t = i >> 5, ci = t / 3, k = t - 3 * ci;
        wsf[j] = w3[(c * 16 + ci) * 3 + k] * (g3[c] * rsqrtf(v3[c] + EPS_BN));
    } else if (j >= 2272 && j < 2304) {
        int c = j - 2272;
        float inv = g3[c] * rsqrtf(v3[c] + EPS_BN);
        wsf[j] = (b3[c] - m3[c]) * inv + be3[c];
    } else if (j >= 2560 && j < 3072) {
        int idx = j - 2560, T = idx >> 6, j6 = idx & 63, row = j6 & 15, q = j6 >> 4;
        const float* src = w_ih + (size_t)(16 * T + row) * 32 + 8 * q;
        unsigned* dst = (unsigned*)(wsf + PK_WIH) + (size_t)idx * 4;
        #pragma unroll
        for (int i = 0; i < 4; i++) dst[i] = pack_bf16(src[2 * i], src[2 * i + 1]);
    } else if (j >= 3072 && j < 3584) {
        int idx = j - 3072, T = idx >> 6, j6 = idx & 63, row = j6 & 15, q = j6 >> 4;
        const float* src = w_hh + (size_t)(16 * T + row) * 32 + 8 * q;
        unsigned* dst = (unsigned*)(wsf + PK_WHH) + (size_t)idx * 4;
        #pragma unroll
        for (int i = 0; i < 4; i++) dst[i] = pack_bf16(src[2 * i], src[2 * i + 1]);
    } else if (j >= 3584 && j < 4096) {
        int idx = j - 3584, f = idx >> 6, j6 = idx & 63, row = j6 & 15, q = j6 >> 4;
        int T = f >> 1, s = f & 1;
        const float* src = fc1w + (size_t)(16 * T + row) * 64 + 32 * s + 8 * q;
        unsigned* dst = (unsigned*)(wsf + PK_FC1) + (size_t)idx * 4;
        #pragma unroll
        for (int i = 0; i < 4; i++) dst[i] = pack_bf16(src[2 * i], src[2 * i + 1]);
    } else if (j >= 4096 && j < 4352) {
        int idx = j - 4096, f = idx >> 6, j6 = idx & 63, row = j6 & 15, q = j6 >> 4;
        int T = f >> 1, s = f & 1;
        const float* src = fc2w + (size_t)(16 * T + row) * 64 + 32 * s + 8 * q;
        unsigned* dst = (unsigned*)(wsf + PK_FC2) + (size_t)idx * 4;
        #pragma unroll
        for (int i = 0; i < 4; i++) dst[i] = pack_bf16(src[2 * i], src[2 * i + 1]);
    } else if (j >= 4352 && j < 4416) {
        int j6 = j - 4352, row = j6 & 15, q = j6 >> 4;
        const float* src = fc3w + (size_t)(row & 3) * 32 + 8 * q;
        unsigned* dst = (unsigned*)(wsf + PK_FC3) + (size_t)j6 * 4;
        #pragma unroll
        for (int i = 0; i < 4; i++) dst[i] = pack_bf16(src[2 * i], src[2 * i + 1]);
    } else if (j >= 4416 && j < 4448) {
        int idx = j - 4416, T = idx >> 2, q = idx & 3;
        #pragma unroll
        for (int i = 0; i < 4; i++)
            wsf[PK_BFR + idx * 4 + i] = b_ih[16 * T + 4 * q + i] + b_hh[16 * T + 4 * q + i];
    } else if (j >= 4448 && j < 4464) {
        int idx = j - 4448, T = idx >> 2, q = idx & 3;
        #pragma unroll
        for (int i = 0; i < 4; i++) wsf[PK_B1 + idx * 4 + i] = fc1b[16 * T + 4 * q + i];
    } else if (j >= 4464 && j < 4472) {
        int idx = j - 4464, T = idx >> 2, q = idx & 3;
        #pragma unroll
        for (int i = 0; i < 4; i++) wsf[PK_B2 + idx * 4 + i] = fc2b[16 * T + 4 * q + i];
    } else if (j == 4472) {
        #pragma unroll
        for (int i = 0; i < 4; i++) wsf[PK_B3 + i] = fc3b[i];
    }
}

// ---------------------------------------------------------------------------
// Kernel 1: conv stack + LIF (r12/r15 sliding-tile 2-batch version — best
// measured conv: ~43 us, 19.4 KB LDS, 8 blocks/CU).
// ---------------------------------------------------------------------------
__device__ inline f32x2 pkfma(f32x2 a, f32x2 b, f32x2 c) {
    return __builtin_elementwise_fma(a, b, c);
}

__device__ inline void conv1_pos(float* __restrict__ c1t,
                                 const float* __restrict__ xb,
                                 const float* __restrict__ wsf,
                                 int p, int idx)
{
    float4 gb = *reinterpret_cast<const float4*>(xb + 4 * p);
    float4 ga = make_float4(0.f, 0.f, 0.f, 0.f);
    if (p > 0) ga = *reinterpret_cast<const float4*>(xb + 4 * p - 4);
    float win[7] = {ga.y, ga.z, ga.w, gb.x, gb.y, gb.z, gb.w};
    #pragma unroll
    for (int cp = 0; cp < 4; cp++) {
        f32x2 acc = *reinterpret_cast<const f32x2*>(wsf + 64 + 2 * cp);
        #pragma unroll
        for (int k = 0; k < 7; k++) {
            f32x2 wv = *reinterpret_cast<const f32x2*>(wsf + k * 8 + 2 * cp);
            f32x2 sv = {win[k], win[k]};
            acc = pkfma(wv, sv, acc);
        }
        c1t[(2 * cp + 0) * 148 + PADX(idx)] = fmaxf(acc[0], 0.f);
        c1t[(2 * cp + 1) * 148 + PADX(idx)] = fmaxf(acc[1], 0.f);
    }
}

__global__ __launch_bounds__(256) void conv_lif_kernel(
    const float* __restrict__ x,
    float* __restrict__ wsf,
    float* __restrict__ spatial_out,
    unsigned int* __restrict__ spk)
{
    __shared__ alignas(16) float smem[4812];
    float* const c1b = smem;
    float* const c3b = smem;
    float* const c2b = smem + 2376;

    const int b0  = blockIdx.x * 2;
    const int tid = threadIdx.x;
    const float* xg0 = x + (size_t)b0 * 1024;
    const float* xg1 = x + (size_t)(b0 + 1) * 1024;

    #pragma unroll
    for (int h = 0; h < 2; h++) {
        {
            const int be = tid >> 7;
            const int lp = tid & 127;
            const float* xb = be ? xg1 : xg0;
            float* c1t = c1b + be * 1188;
            const int p = 126 * h + lp;
            conv1_pos(c1t, xb, wsf, p, p + 2 - 128 * h);
            if (h == 1 && lp == 0)
                conv1_pos(c1t, xb, wsf, 254, 128);
            if (h == 0 && lp < 2) {
                #pragma unroll
                for (int ch = 0; ch < 8; ch++) c1t[ch * 148 + lp] = 0.f;
            }
        }
        __syncthreads();

        {
            const int Pl = tid & 31;
            const int be = (tid >> 5) & 1;
            const int cq = __builtin_amdgcn_readfirstlane(tid >> 6) << 2;
            const int P  = 32 * h + Pl;
            const float* wB2 = wsf + 80;
            const float* bB2 = wsf + 720;
            f32x2 a01 = *reinterpret_cast<const f32x2*>(bB2 + cq);
            f32x2 a23 = *reinterpret_cast<const f32x2*>(bB2 + cq + 2);
            const float* c1t = c1b + be * 1188;
            float* c2t = c2b + be * 1220;
            if (h == 0 && Pl == 0) {
                #pragma unroll
                for (int j = 0; j < 4; j++) c2t[(cq + j) * 76] = 0.f;
            }
            #pragma unroll
            for (int ci = 0; ci < 8; ci++) {
                const float* row = c1t + ci * 148;
                float4 va = *reinterpret_cast<const float4*>(&row[PADX(4 * Pl)]);
                float  v4 = row[PADX(4 * Pl + 4)];
                float win[5] = {va.x, va.y, va.z, va.w, v4};
                #pragma unroll
                for (int k = 0; k < 5; k++) {
                    const float* wp = wB2 + (ci * 5 + k) * 16 + cq;
                    f32x2 sv = {win[k], win[k]};
                    a01 = pkfma(*reinterpret_cast<const f32x2*>(wp),     sv, a01);
                    a23 = pkfma(*reinterpret_cast<const f32x2*>(wp + 2), sv, a23);
                }
            }
            c2t[(cq + 0) * 76 + PADX(1 + P)] = fmaxf(a01[0], 0.f);
            c2t[(cq + 1) * 76 + PADX(1 + P)] = fmaxf(a01[1], 0.f);
            c2t[(cq + 2) * 76 + PADX(1 + P)] = fmaxf(a23[0], 0.f);
            c2t[(cq + 3) * 76 + PADX(1 + P)] = fmaxf(a23[1], 0.f);
        }
        __syncthreads();
    }

    {
        const int pl  = tid & 63;
        const int be  = pl >> 5;
        const int pos = pl & 31;
        const int cb  = __builtin_amdgcn_readfirstlane(tid >> 6) << 3;
        const float* wC3 = wsf + 736;
        const float* bC3 = wsf + 2272;
        f32x2 a01 = *reinterpret_cast<const f32x2*>(bC3 + cb);
        f32x2 a23 = *reinterpret_cast<const f32x2*>(bC3 + cb + 2);
        f32x2 a45 = *reinterpret_cast<const f32x2*>(bC3 + cb + 4);
        f32x2 a67 = *reinterpret_cast<const f32x2*>(bC3 + cb + 6);
        const float* c2t = c2b + be * 1220;
        #pragma unroll
        for (int ci = 0; ci < 16; ci++) {
            const float* row = c2t + ci * 76;
            float2 vab = *reinterpret_cast<const float2*>(&row[PADX(2 * pos)]);
            float  vc  = row[PADX(2 * pos + 2)];
            float win[3] = {vab.x, vab.y, vc};
            #pragma unroll
            for (int k = 0; k < 3; k++) {
                const float* wp = wC3 + (ci * 3 + k) * 32 + cb;
                f32x2 sv = {win[k], win[k]};
                a01 = pkfma(*reinterpret_cast<const f32x2*>(wp),     sv, a01);
                a23 = pkfma(*reinterpret_cast<const f32x2*>(wp + 2), sv, a23);
                a45 = pkfma(*reinterpret_cast<const f32x2*>(wp + 4), sv, a45);
                a67 = pkfma(*reinterpret_cast<const f32x2*>(wp + 6), sv, a67);
            }
        }
        float* c3t = c3b + be * 1060;
        c3t[(cb + 0) * 33 + pos] = fmaxf(a01[0], 0.f);
        c3t[(cb + 1) * 33 + pos] = fmaxf(a01[1], 0.f);
        c3t[(cb + 2) * 33 + pos] = fmaxf(a23[0], 0.f);
        c3t[(cb + 3) * 33 + pos] = fmaxf(a23[1], 0.f);
        c3t[(cb + 4) * 33 + pos] = fmaxf(a45[0], 0.f);
        c3t[(cb + 5) * 33 + pos] = fmaxf(a45[1], 0.f);
        c3t[(cb + 6) * 33 + pos] = fmaxf(a67[0], 0.f);
        c3t[(cb + 7) * 33 + pos] = fmaxf(a67[1], 0.f);
    }
    __syncthreads();

    if (tid < 64) {
        const int be = tid >> 5, ch = tid & 31;
        const float* c3t = c3b + be * 1060;
        float s = 0.f;
        #pragma unroll
        for (int t = 0; t < 32; t++) s += c3t[ch * 33 + t];
        float sv = s * 0.03125f;
        spatial_out[(size_t)(b0 + be) * 32 + ch] = sv;
        union { __bf16 h; unsigned short u; } cv;
        cv.h = (__bf16)sv;
        ((unsigned short*)(wsf + PK_SPB))[(size_t)(b0 + be) * 32 + ch] = cv.u;

        float mem = 0.f;
        #pragma unroll
        for (int t = 0; t < 32; t++) {
            mem = __fadd_rn(__fmul_rn(0.9f, mem), c3t[ch * 33 + t]);
            bool spike = mem > 0.5f;
            mem = spike ? 0.f : mem;
            unsigned long long msk = __ballot(spike);
            if (tid == 0) {
                spk[(size_t)b0 * 32 + t]      = (unsigned int)(msk & 0xffffffffull);
                spk[(size_t)b0 * 32 + 32 + t] = (unsigned int)(msk >> 32);
            }
        }
    }
}

// ---------------------------------------------------------------------------
// Kernel 2: MFMA LSTM + FC head — 4-wave gate-split (r15, best measured).
// ---------------------------------------------------------------------------
__device__ inline float sigm(float x) {
    return __builtin_amdgcn_rcpf(1.f + __expf(-x));
}
__device__ inline float tanh_(float x) {
    return fmaf(2.f, __builtin_amdgcn_rcpf(1.f + __expf(-2.f * x)), -1.f);
}

__global__ __launch_bounds__(256, 2) void lstm_fc_mfma_kernel(
    const unsigned int* __restrict__ spk,   // [B][32]
    const float* __restrict__ wsf,          // prepacked weights + spatial_bf
    float* __restrict__ out0,               // [B][4]
    float* __restrict__ hlast_out)          // [B][32]
{
    const int ltid = threadIdx.x;
    const int l    = ltid & 63;
    const int g    = ltid >> 6;             // wave = gate (0=i,1=f,2=g,3=o)
    const int row  = l & 15;
    const int q    = l >> 4;
    const int base = blockIdx.x * 16;

    __shared__ unsigned int mlds[512];           // [t][16]
    __shared__ alignas(16) __bf16 hdb[640];      // h: [16][40]
    __shared__ alignas(16) float  actb[2304];    // acts: [4][16][36]
    __shared__ alignas(16) __bf16 zlds[1152];    // fc1 out: [16][72]

    for (int i = ltid; i < 512; i += 256) {
        int j = i >> 5, t = i & 31;
        mlds[t * 16 + j] = spk[(size_t)(base + j) * 32 + t];
    }
    for (int i = ltid; i < 640; i += 256) hdb[i] = (__bf16)0.f;

    union bc { u32x4 u; bf16x8 v; };
    const u32x4* wihp = (const u32x4*)(wsf + PK_WIH);
    const u32x4* whhp = (const u32x4*)(wsf + PK_WHH);

    const int T0 = 2 * g, T1 = 2 * g + 1;
    bf16x8 wih0, wih1, whh0, whh1;
    { bc a; a.u = wihp[T0 * 64 + l]; wih0 = a.v; }
    { bc a; a.u = wihp[T1 * 64 + l]; wih1 = a.v; }
    { bc a; a.u = whhp[T0 * 64 + l]; whh0 = a.v; }
    { bc a; a.u = whhp[T1 * 64 + l]; whh1 = a.v; }
    f32x4 bfr0 = *reinterpret_cast<const f32x4*>(wsf + PK_BFR + (T0 * 4 + q) * 4);
    f32x4 bfr1 = *reinterpret_cast<const f32x4*>(wsf + PK_BFR + (T1 * 4 + q) * 4);

    const float as = (g == 2) ? 2.f : 1.f;
    const float am = (g == 2) ? 2.f : 1.f;
    const float ac = (g == 2) ? -1.f : 0.f;

    const int crow = ltid & 15, cci = ltid >> 4;
    float cst0 = 0.f, cst1 = 0.f, h0 = 0.f, h1 = 0.f;

    __syncthreads();

    #pragma unroll 1
    for (int t = 0; t < 32; t++) {
        unsigned int m  = mlds[t * 16 + row];
        unsigned int by = (m >> (q * 8)) & 0xFFu;
        union { bf16x8 v; unsigned int u[4]; } a1;
        a1.u[0] = ((by & 1u)        * 0x3F80u) | (((by >> 1) & 1u) * 0x3F800000u);
        a1.u[1] = (((by >> 2) & 1u) * 0x3F80u) | (((by >> 3) & 1u) * 0x3F800000u);
        a1.u[2] = (((by >> 4) & 1u) * 0x3F80u) | (((by >> 5) & 1u) * 0x3F800000u);
        a1.u[3] = (((by >> 6) & 1u) * 0x3F80u) | (((by >> 7) & 1u) * 0x3F800000u);
        bf16x8 a2 = *reinterpret_cast<bf16x8*>(&hdb[row * 40 + q * 8]);

        f32x4 acc0 = __builtin_amdgcn_mfma_f32_16x16x32_bf16(wih0, a1.v, bfr0, 0, 0, 0);
        acc0       = __builtin_amdgcn_mfma_f32_16x16x32_bf16(whh0, a2,   acc0, 0, 0, 0);
        f32x4 acc1 = __builtin_amdgcn_mfma_f32_16x16x32_bf16(wih1, a1.v, bfr1, 0, 0, 0);
        acc1       = __builtin_amdgcn_mfma_f32_16x16x32_bf16(whh1, a2,   acc1, 0, 0, 0);

        f32x4 e0, e1;
        #pragma unroll
        for (int j = 0; j < 4; j++) {
            e0[j] = fmaf(am, sigm(as * acc0[j]), ac);
            e1[j] = fmaf(am, sigm(as * acc1[j]), ac);
        }
        *reinterpret_cast<f32x4*>(&actb[g * 576 + row * 36 + 4 * q])      = e0;
        *reinterpret_cast<f32x4*>(&actb[g * 576 + row * 36 + 16 + 4 * q]) = e1;
        __syncthreads();

        {
            float iv0 = actb[0 * 576 + crow * 36 + cci];
            float fv0 = actb[1 * 576 + crow * 36 + cci];
            float gv0 = actb[2 * 576 + crow * 36 + cci];
            float ov0 = actb[3 * 576 + crow * 36 + cci];
            float iv1 = actb[0 * 576 + crow * 36 + 16 + cci];
            float fv1 = actb[1 * 576 + crow * 36 + 16 + cci];
            float gv1 = actb[2 * 576 + crow * 36 + 16 + cci];
            float ov1 = actb[3 * 576 + crow * 36 + 16 + cci];
            cst0 = fmaf(fv0, cst0, iv0 * gv0);
            h0   = ov0 * tanh_(cst0);
            cst1 = fmaf(fv1, cst1, iv1 * gv1);
            h1   = ov1 * tanh_(cst1);
            hdb[crow * 40 + cci]      = (__bf16)h0;
            hdb[crow * 40 + 16 + cci] = (__bf16)h1;
        }
        __syncthreads();
    }

    hlast_out[(size_t)(base + crow) * 32 + cci]      = h0;
    hlast_out[(size_t)(base + crow) * 32 + 16 + cci] = h1;

    bf16x8 hf = *reinterpret_cast<bf16x8*>(&hdb[row * 40 + 8 * q]);
    bf16x8 spf;
    {
        bc s_;
        s_.u = *reinterpret_cast<const u32x4*>(
            (const unsigned short*)(wsf + PK_SPB) + (size_t)(base + row) * 32 + 8 * q);
        spf = s_.v;
    }

    const u32x4* fc1p = (const u32x4*)(wsf + PK_FC1);
    {
        const int T = g;
        bc x0_, x1_;
        x0_.u = fc1p[(T * 2 + 0) * 64 + l];
        x1_.u = fc1p[(T * 2 + 1) * 64 + l];
        f32x4 c = *reinterpret_cast<const f32x4*>(wsf + PK_B1 + (T * 4 + q) * 4);
        f32x4 a = __builtin_amdgcn_mfma_f32_16x16x32_bf16(x0_.v, hf,  c, 0, 0, 0);
        a       = __builtin_amdgcn_mfma_f32_16x16x32_bf16(x1_.v, spf, a, 0, 0, 0);
        bf16x4 zv;
        #pragma unroll
        for (int i = 0; i < 4; i++) zv[i] = (__bf16)fmaxf(a[i], 0.f);
        *reinterpret_cast<bf16x4*>(&zlds[row * 72 + 16 * T + 4 * q]) = zv;
    }
    __syncthreads();
    bf16x8 z1f0 = *reinterpret_cast<bf16x8*>(&zlds[row * 72 + 8 * q]);
    bf16x8 z1f1 = *reinterpret_cast<bf16x8*>(&zlds[row * 72 + 32 + 8 * q]);

    __bf16* z2b = (__bf16*)actb;
    const u32x4* fc2p = (const u32x4*)(wsf + PK_FC2);
    if (g < 2) {
        const int T = g;
        bc x0_, x1_;
        x0_.u = fc2p[(T * 2 + 0) * 64 + l];
        x1_.u = fc2p[(T * 2 + 1) * 64 + l];
        f32x4 c = *reinterpret_cast<const f32x4*>(wsf + PK_B2 + (T * 4 + q) * 4);
        f32x4 a = __builtin_amdgcn_mfma_f32_16x16x32_bf16(x0_.v, z1f0, c, 0, 0, 0);
        a       = __builtin_amdgcn_mfma_f32_16x16x32_bf16(x1_.v, z1f1, a, 0, 0, 0);
        bf16x4 zv;
        #pragma unroll
        for (int i = 0; i < 4; i++) zv[i] = (__bf16)fmaxf(a[i], 0.f);
        *reinterpret_cast<bf16x4*>(&z2b[row * 40 + 16 * T + 4 * q]) = zv;
    }
    __syncthreads();

    if (g == 0) {
        bf16x8 z2f = *reinterpret_cast<bf16x8*>(&z2b[row * 40 + 8 * q]);
        bc x3_;
        x3_.u = ((const u32x4*)(wsf + PK_FC3))[l];
        f32x4 c = *reinterpret_cast<const f32x4*>(wsf + PK_B3);
        f32x4 o = __builtin_amdgcn_mfma_f32_16x16x32_bf16(x3_.v, z2f, c, 0, 0, 0);
        if (l < 16)
            *reinterpret_cast<f32x4*>(out0 + (size_t)(base + row) * 4) = o;
    }
}

// ---------------------------------------------------------------------------
extern "C" void kernel_launch(void* const* d_in, const int* in_sizes, int n_in,
                              void* d_out, int out_size, void* d_ws, size_t ws_size,
                              hipStream_t stream) {
    const float* x    = (const float*)d_in[0];
    const float* w1   = (const float*)d_in[1];
    const float* b1   = (const float*)d_in[2];
    const float* g1   = (const float*)d_in[3];
    const float* be1  = (const float*)d_in[4];
    const float* m1   = (const float*)d_in[5];
    const float* v1   = (const float*)d_in[6];
    const float* w2   = (const float*)d_in[7];
    const float* b2   = (const float*)d_in[8];
    const float* g2   = (const float*)d_in[9];
    const float* be2  = (const float*)d_in[10];
    const float* m2   = (const float*)d_in[11];
    const float* v2   = (const float*)d_in[12];
    const float* w3   = (const float*)d_in[13];
    const float* b3   = (const float*)d_in[14];
    const float* g3   = (const float*)d_in[15];
    const float* be3  = (const float*)d_in[16];
    const float* m3   = (const float*)d_in[17];
    const float* v3   = (const float*)d_in[18];
    const float* w_ih = (const float*)d_in[19];
    const float* w_hh = (const float*)d_in[20];
    const float* b_ih = (const float*)d_in[21];
    const float* b_hh = (const float*)d_in[22];
    const float* fc1w = (const float*)d_in[23];
    const float* fc1b = (const float*)d_in[24];
    const float* fc2w = (const float*)d_in[25];
    const float* fc2b = (const float*)d_in[26];
    const float* fc3w = (const float*)d_in[27];
    const float* fc3b = (const float*)d_in[28];

    float* out0    = (float*)d_out;                 // [8192][4]
    float* spatial = out0 + (size_t)NB * 4;         // [8192][32]
    float* hlast   = spatial + (size_t)NB * 32;     // [8192][32]
    unsigned int* spk = (unsigned int*)d_ws;        // [8192][32] bitmasks
    float* wsf = (float*)d_ws + WSF_OFF;            // folded + prepacked weights

    hipLaunchKernelGGL(fold_kernel, dim3(18), dim3(256), 0, stream,
                       w1, b1, g1, be1, m1, v1,
                       w2, b2, g2, be2, m2, v2,
                       w3, b3, g3, be3, m3, v3,
                       w_ih, w_hh, b_ih, b_hh,
                       fc1w, fc1b, fc2w, fc2b, fc3w, fc3b, wsf);

    hipLaunchKernelGGL(conv_lif_kernel, dim3(NB / 2), dim3(256), 0, stream,
                       x, wsf, spatial, spk);

    hipLaunchKernelGGL(lstm_fc_mfma_kernel, dim3(NB / 16), dim3(256), 0, stream,
                       spk, wsf, out0, hlast);
}